// Round 12
// baseline (198.585 us; speedup 1.0000x reference)
//
#include <hip/hip_runtime.h>
#include <stdint.h>

typedef __attribute__((ext_vector_type(8))) short short8;
typedef __attribute__((ext_vector_type(2))) float float2v;
typedef __attribute__((ext_vector_type(4))) float float4v;
typedef __attribute__((ext_vector_type(16))) float f32x16;
typedef __attribute__((ext_vector_type(2))) uint32_t uint32x2;
typedef __attribute__((ext_vector_type(4))) uint32_t uint32x4;
typedef __attribute__((ext_vector_type(2))) unsigned int uint2v;

// v_cvt_pk_bf16_f32: 2 f32 -> packed 2x bf16 (RNE), single VALU op.
__device__ __forceinline__ uint32_t pkbf(float a, float b) {
  uint32_t r;
  asm("v_cvt_pk_bf16_f32 %0, %1, %2" : "=v"(r) : "v"(a), "v"(b));
  return r;
}

// packed 2xf32 add (VOP3P) for the softmax row-sum accumulation.
__device__ __forceinline__ float2v pkadd(float2v a, float2v b) {
  float2v d;
  asm("v_pk_add_f32 %0, %1, %2" : "=v"(d) : "v"(a), "v"(b));
  return d;
}

__device__ __forceinline__ float fexp2(float x) {
#if __has_builtin(__builtin_amdgcn_exp2f)
  return __builtin_amdgcn_exp2f(x);
#else
  return exp2f(x);
#endif
}

// permlane32_swap: exchanges vdst's high 32 lanes with vsrc's low 32 lanes.
__device__ __forceinline__ uint2v plswap(uint32_t a, uint32_t b) {
#if __has_builtin(__builtin_amdgcn_permlane32_swap)
  return __builtin_amdgcn_permlane32_swap(a, b, false, false);
#else
  asm("v_permlane32_swap_b32 %0, %1" : "+v"(a), "+v"(b));
  uint2v r;
  r[0] = a;
  r[1] = b;
  return r;
#endif
}

__device__ __forceinline__ void gll16(const unsigned short* g, unsigned short* l) {
  __builtin_amdgcn_global_load_lds(
      (const __attribute__((address_space(1))) void*)g,
      (__attribute__((address_space(3))) void*)l, 16, 0, 0);
}

__device__ __forceinline__ void gll16f(const float* g, float* l) {
  __builtin_amdgcn_global_load_lds(
      (const __attribute__((address_space(1))) void*)g,
      (__attribute__((address_space(3))) void*)l, 16, 0, 0);
}

// ---------------------------------------------------------------------------
// Fused QKV projection, fp32 inputs consumed DIRECTLY.  R12: cvt_all is
// deleted -- fp32 x/W tiles are DMA'd raw into LDS (cell-swizzled
// c ^= row&15 at 16B granularity, pre-swizzled global source) and converted
// bf16 at FRAGMENT-READ time (2x ds_read_b128 + 4x cvt_pk per fragment).
// Unlike R7/R8 (reg-staged convert in the serial staging phase), the cvt
// now sits in the compute phase where MfmaUtil=10%/VALUBusy=11% showed
// ~80% slack.  Numerically bit-identical to the old cvt_all path.
// 64x64 tile, grid (64,12,3)=2304 blocks, LDS 32KB -> 5 blocks/CU.
// z=0 -> Qp (scaled), z=1 -> Kp, z=2 -> Vt [N][M].
// ---------------------------------------------------------------------------
__global__ __launch_bounds__(256) void gemm_qkv(
    const float* __restrict__ xq, const float* __restrict__ xk,
    const float* __restrict__ xv,
    const float* __restrict__ wq, const float* __restrict__ wk,
    const float* __restrict__ wv,
    const float* __restrict__ bq, const float* __restrict__ bk,
    const float* __restrict__ bv,
    unsigned short* __restrict__ Qp, unsigned short* __restrict__ Kp,
    unsigned short* __restrict__ Vt, float qscale)
{
  __shared__ float Asf[64 * 64];   // fp32 A tile, 16KB
  __shared__ float Wsf[64 * 64];   // fp32 W tile, 16KB
  const int z = blockIdx.z;
  const float* A = z == 0 ? xq : z == 1 ? xk : xv;
  const float* W = z == 0 ? wq : z == 1 ? wk : wv;
  const float* bias = z == 0 ? bq : z == 1 ? bk : bv;
  const int M = 4096, N = 768, K = 768;
  const int tid = threadIdx.x, wave = tid >> 6, lane = tid & 63;
  const int g = lane >> 4, l16 = lane & 15;
  const int m0 = blockIdx.x * 64, n0 = blockIdx.y * 64;
  const int wm = (wave & 1) * 32, wn = (wave >> 1) * 32;

  // fragment: 8 logical fp32 (cols gg*8..+7) of row -> bf16 short8.
  // LDS cell cs holds logical cell cs^(row&15); reader XORs back.
  auto f32frag = [&](const float* lds, int row, int gg) -> short8 {
    const int s = row & 15;
    const float4v a = *(const float4v*)&lds[row * 64 + (((2 * gg) ^ s) << 2)];
    const float4v b = *(const float4v*)&lds[row * 64 + (((2 * gg + 1) ^ s) << 2)];
    union { uint32x4 u; short8 sv; } w;
    w.u[0] = pkbf(a[0], a[1]);
    w.u[1] = pkbf(a[2], a[3]);
    w.u[2] = pkbf(b[0], b[1]);
    w.u[3] = pkbf(b[2], b[3]);
    return w.sv;
  };

  float4v acc[2][2] = {};

  for (int k0 = 0; k0 < K; k0 += 64) {
    if (k0) __syncthreads();
    // DMA-stage both fp32 tiles: 1024 cells each, 4 rounds x 256 lanes.
    // LDS dest linear (wave-uniform base + lane*16B); global source carries
    // the swizzle: cell c of row holds logical cell c^(row&15).
    #pragma unroll
    for (int rr = 0; rr < 4; ++rr) {
      const int row = rr * 16 + wave * 4 + (lane >> 4);
      const int cl = (lane & 15) ^ (row & 15);
      gll16f(A + (size_t)(m0 + row) * K + k0 + cl * 4,
             &Asf[(rr * 16 + wave * 4) * 64]);
      gll16f(W + (size_t)(n0 + row) * K + k0 + cl * 4,
             &Wsf[(rr * 16 + wave * 4) * 64]);
    }
    __syncthreads();
    #pragma unroll
    for (int kk = 0; kk < 2; ++kk) {
      const int gg = kk * 4 + g;
      short8 xf[2], wf[2];
      #pragma unroll
      for (int t = 0; t < 2; ++t) {
        xf[t] = f32frag(Asf, wm + t * 16 + l16, gg);
        wf[t] = f32frag(Wsf, wn + t * 16 + l16, gg);
      }
      if (z < 2) {
        #pragma unroll
        for (int i = 0; i < 2; ++i)
          #pragma unroll
          for (int j = 0; j < 2; ++j)
            acc[i][j] = __builtin_amdgcn_mfma_f32_16x16x32_bf16(wf[i], xf[j], acc[i][j], 0, 0, 0);
      } else {
        #pragma unroll
        for (int b = 0; b < 2; ++b)
          #pragma unroll
          for (int a2 = 0; a2 < 2; ++a2)
            acc[b][a2] = __builtin_amdgcn_mfma_f32_16x16x32_bf16(xf[a2], wf[b], acc[b][a2], 0, 0, 0);
      }
    }
  }

  if (z < 2) {
    // C layout: col=l16 -> m, row=4g+rr -> n.
    unsigned short* O = z == 0 ? Qp : Kp;
    const float osc = z == 0 ? qscale : 1.0f;
    #pragma unroll
    for (int i = 0; i < 2; ++i) {
      const int nb = n0 + wn + i * 16 + 4 * g;
      const float4v bb = *(const float4v*)&bias[nb];
      #pragma unroll
      for (int j = 0; j < 2; ++j) {
        const int m = m0 + wm + j * 16 + l16;
        uint32x2 pk;
        pk[0] = pkbf((acc[i][j][0] + bb[0]) * osc, (acc[i][j][1] + bb[1]) * osc);
        pk[1] = pkbf((acc[i][j][2] + bb[2]) * osc, (acc[i][j][3] + bb[3]) * osc);
        *(uint32x2*)(O + (size_t)m * N + nb) = pk;
      }
    }
  } else {
    // C layout: col=l16 -> n, row=4g+rr -> m.
    #pragma unroll
    for (int b = 0; b < 2; ++b) {
      const int n = n0 + wn + b * 16 + l16;
      const float bb = bias[n];
      #pragma unroll
      for (int a2 = 0; a2 < 2; ++a2) {
        const int mb = m0 + wm + a2 * 16 + 4 * g;
        uint32x2 pk;
        pk[0] = pkbf(acc[b][a2][0] + bb, acc[b][a2][1] + bb);
        pk[1] = pkbf(acc[b][a2][2] + bb, acc[b][a2][3] + bb);
        *(uint32x2*)(Vt + (size_t)n * M + mb) = pk;
      }
    }
  }
}

// ---------------------------------------------------------------------------
// Flash attention PARTIAL kernel (R2 body, 47.3us verified; frozen --
// KVBLK=128, 2-deep pipeline, and re-chunking all measured worse).
// Fixed softmax (p = exp2(s)); swapped QK^T; in-register P (T12); PV via
// 32x32x16 with V^T A-frags from swizzled LDS. 32KB LDS -> 4 blocks/CU.
// ---------------------------------------------------------------------------
__global__ __launch_bounds__(256, 4) void flash_part(
    const unsigned short* __restrict__ Qp,  // [S][768] bf16, pre-scaled
    const unsigned short* __restrict__ Kp,  // [S][768] bf16
    const unsigned short* __restrict__ Vt,  // [768][S] bf16
    unsigned short* __restrict__ Opart,     // [1536 slots][128][64] bf16
    float* __restrict__ lpart)              // [1536 slots][128] fp32
{
  __shared__ unsigned short lds_k[2][64 * 64];
  __shared__ unsigned short lds_v[2][64 * 64];
  const int S = 4096, DM = 768;

  const int gid = blockIdx.x;
  const int h = gid % 12;
  const int e = 79 - gid / 12;
  int t, c;
  if (e < 8)       { t = e;                c = 0; }
  else if (e < 24) { t = 8 + (e - 8) / 2;  c = (e - 8) % 2; }
  else if (e < 48) { t = 16 + (e - 24) / 3; c = (e - 24) % 3; }
  else             { t = 24 + (e - 48) / 4; c = (e - 48) % 4; }
  const int kb0 = c * 16;
  const int kbe = min(kb0 + 16, 2 * t + 2);

  const int tid = threadIdx.x, wave = tid >> 6, lane = tid & 63;
  const int l31 = lane & 31, hi = lane >> 5, sw7 = lane & 7;
  const int qbase = t * 128 + wave * 32;
  const int qrow = qbase + l31;

  short8 qf[4];
  {
    const unsigned short* qp = Qp + (size_t)qrow * DM + h * 64 + hi * 8;
    qf[0] = *(const short8*)(qp);
    qf[1] = *(const short8*)(qp + 16);
    qf[2] = *(const short8*)(qp + 32);
    qf[3] = *(const short8*)(qp + 48);
  }

  f32x16 o0 = {}, o1 = {};            // O^T[d][q], d-tiles 0..31 / 32..63
  float2v lsA = {0.f, 0.f}, lsB = {0.f, 0.f};

  const int strow = wave * 16 + (lane >> 3);
  const int skg = lane & 7;

  #pragma unroll
  for (int cc = 0; cc < 2; ++cc) {
    const int row = strow + cc * 8;
    const int kg = skg ^ (row & 7);
    gll16(Kp + (size_t)(kb0 * 64 + row) * DM + h * 64 + kg * 8,
          &lds_k[0][(wave * 16 + cc * 8) * 64]);
    gll16(Vt + (size_t)(h * 64 + row) * S + kb0 * 64 + kg * 8,
          &lds_v[0][(wave * 16 + cc * 8) * 64]);
  }
  __syncthreads();

  for (int kb = kb0; kb < kbe; ++kb) {
    const int cur = kb & 1;
    if (kb + 1 < kbe) {
      const int nb = cur ^ 1;
      #pragma unroll
      for (int cc = 0; cc < 2; ++cc) {
        const int row = strow + cc * 8;
        const int kg = skg ^ (row & 7);
        gll16(Kp + (size_t)((kb + 1) * 64 + row) * DM + h * 64 + kg * 8,
              &lds_k[nb][(wave * 16 + cc * 8) * 64]);
        gll16(Vt + (size_t)(h * 64 + row) * S + (kb + 1) * 64 + kg * 8,
              &lds_v[nb][(wave * 16 + cc * 8) * 64]);
      }
    }
    const unsigned short* kc = lds_k[cur];
    const unsigned short* vc = lds_v[cur];

    f32x16 s0 = {}, s1 = {};
    __builtin_amdgcn_s_setprio(1);
    #pragma unroll
    for (int d4 = 0; d4 < 4; ++d4) {
      const int cg = ((2 * d4 + hi) ^ sw7) * 8;
      short8 ka = *(const short8*)&kc[l31 * 64 + cg];
      short8 kb2 = *(const short8*)&kc[(32 + l31) * 64 + cg];
      s0 = __builtin_amdgcn_mfma_f32_32x32x16_bf16(ka, qf[d4], s0, 0, 0, 0);
      s1 = __builtin_amdgcn_mfma_f32_32x32x16_bf16(kb2, qf[d4], s1, 0, 0, 0);
    }
    __builtin_amdgcn_s_setprio(0);

    const bool diag = (kb + 1) * 64 > qbase;
    short8 pb[4];
    auto sm_pack = [&](const f32x16& sv, int ks, short8* pbp) {
      #pragma unroll
      for (int jh = 0; jh < 2; ++jh) {
        float pe[8];
        if (diag) {
          #pragma unroll
          for (int rr = 0; rr < 8; ++rr) {
            const int key = kb * 64 + ks + (rr & 3) + 8 * (2 * jh + (rr >> 2)) + 4 * hi;
            pe[rr] = fexp2(key <= qrow ? sv[jh * 8 + rr] : -1e30f);
          }
        } else {
          #pragma unroll
          for (int rr = 0; rr < 8; ++rr) pe[rr] = fexp2(sv[jh * 8 + rr]);
        }
        float2v p01 = {pe[0], pe[1]}, p23 = {pe[2], pe[3]};
        float2v p45 = {pe[4], pe[5]}, p67 = {pe[6], pe[7]};
        lsA = pkadd(lsA, pkadd(p01, p45));
        lsB = pkadd(lsB, pkadd(p23, p67));
        const uint32_t x01 = pkbf(pe[0], pe[1]);
        const uint32_t x23 = pkbf(pe[2], pe[3]);
        const uint32_t y01 = pkbf(pe[4], pe[5]);
        const uint32_t y23 = pkbf(pe[6], pe[7]);
        uint2v r01 = plswap(x01, y01);
        uint2v r23 = plswap(x23, y23);
        union { uint32x4 u; short8 s; } w;
        w.u[0] = r01[0];
        w.u[1] = r23[0];
        w.u[2] = r01[1];
        w.u[3] = r23[1];
        pbp[jh] = w.s;
      }
    };
    sm_pack(s0, 0, &pb[0]);
    sm_pack(s1, 32, &pb[2]);

    __builtin_amdgcn_s_setprio(1);
    #pragma unroll
    for (int kk = 0; kk < 4; ++kk) {
      const int cg = ((2 * kk + hi) ^ sw7) * 8;
      short8 va0 = *(const short8*)&vc[l31 * 64 + cg];
      short8 va1 = *(const short8*)&vc[(32 + l31) * 64 + cg];
      o0 = __builtin_amdgcn_mfma_f32_32x32x16_bf16(va0, pb[kk], o0, 0, 0, 0);
      o1 = __builtin_amdgcn_mfma_f32_32x32x16_bf16(va1, pb[kk], o1, 0, 0, 0);
    }
    __builtin_amdgcn_s_setprio(0);

    __syncthreads();  // drain prefetch DMA + protect buffer reuse
  }

  // epilogue: unnormalized partial write
  float L = (lsA[0] + lsA[1]) + (lsB[0] + lsB[1]);
  L += __shfl_xor(L, 32);
  const int slot = (h * 32 + t) * 4 + c;
  if (hi == 0) lpart[slot * 128 + wave * 32 + l31] = L;
  unsigned short* ob = Opart + (size_t)slot * 8192 + (size_t)(wave * 32 + l31) * 64;
  #pragma unroll
  for (int dt = 0; dt < 2; ++dt) {
    const f32x16& oo = dt ? o1 : o0;
    #pragma unroll
    for (int a = 0; a < 4; ++a) {
      uint32x2 ov;
      ov[0] = pkbf(oo[4 * a + 0], oo[4 * a + 1]);
      ov[1] = pkbf(oo[4 * a + 2], oo[4 * a + 3]);
      *(uint32x2*)(ob + dt * 32 + 8 * a + 4 * hi) = ov;
    }
  }
}

// ---------------------------------------------------------------------------
// Combine partials. Grid (64,12), 64 q-rows/block -> 768 blocks = 3/CU.
// ---------------------------------------------------------------------------
__global__ __launch_bounds__(256) void flash_combine(
    const unsigned short* __restrict__ Opart, const float* __restrict__ lpart,
    unsigned short* __restrict__ AO)
{
  const int t2 = blockIdx.x, h = blockIdx.y;
  const int t = t2 >> 1;
  const int nc = (2 * t + 17) >> 4;          // ceil((2t+2)/16)
  const int slot0 = (h * 32 + t) * 4;
  const int tid = threadIdx.x;
  const int qr = tid >> 2, dc = (tid & 3) * 16;
  const int ql = (t2 & 1) * 64 + qr;         // row within the 128-row tile
  float acc[16];
  #pragma unroll
  for (int j = 0; j < 16; ++j) acc[j] = 0.0f;
  float lsum = 0.0f;
  for (int cc = 0; cc < nc; ++cc) {
    const int slot = slot0 + cc;
    lsum += lpart[slot * 128 + ql];
    const uint32x4* p = (const uint32x4*)(Opart + (size_t)slot * 8192 + ql * 64 + dc);
    uint32x4 w0 = p[0], w1 = p[1];
    #pragma unroll
    for (int j = 0; j < 4; ++j) {
      union { uint32_t u; float f; } lo, hi;
      lo.u = w0[j] << 16; hi.u = w0[j] & 0xffff0000u;
      acc[2 * j] += lo.f; acc[2 * j + 1] += hi.f;
      lo.u = w1[j] << 16; hi.u = w1[j] & 0xffff0000u;
      acc[8 + 2 * j] += lo.f; acc[8 + 2 * j + 1] += hi.f;
    }
  }
  const float inv = 1.0f / lsum;
  uint32x4 o0, o1;
  #pragma unroll
  for (int j = 0; j < 4; ++j) {
    o0[j] = pkbf(acc[2 * j] * inv, acc[2 * j + 1] * inv);
    o1[j] = pkbf(acc[8 + 2 * j] * inv, acc[8 + 2 * j + 1] * inv);
  }
  unsigned short* dst = AO + (size_t)(t * 128 + ql) * 768 + h * 64 + dc;
  *(uint32x4*)dst = o0;
  *(uint32x4*)(dst + 8) = o1;
}

// ---------------------------------------------------------------------------
// Output projection: fp32 out = AO(bf16, DMA) * wo(fp32, DMA + fragment-time
// cvt)^T + bo.  64x64 tile, grid (64,12) = 768 blocks. C^T write.
// ---------------------------------------------------------------------------
__global__ __launch_bounds__(256) void gemm_out(
    const unsigned short* __restrict__ A, const float* __restrict__ W,
    const float* __restrict__ bias, float* __restrict__ Out)
{
  __shared__ unsigned short As[64 * 64];   // bf16 A tile, 8KB
  __shared__ float Wsf[64 * 64];           // fp32 W tile, 16KB
  const int N = 768, K = 768;
  const int tid = threadIdx.x, wave = tid >> 6, lane = tid & 63;
  const int g = lane >> 4, l16 = lane & 15;
  const int sw = l16 & 7;
  const int m0 = blockIdx.x * 64, n0 = blockIdx.y * 64;
  const int wm = (wave & 1) * 32, wn = (wave >> 1) * 32;
  const int r8 = lane >> 3, skg = lane & 7;

  auto f32frag = [&](const float* lds, int row, int gg) -> short8 {
    const int s = row & 15;
    const float4v a = *(const float4v*)&lds[row * 64 + (((2 * gg) ^ s) << 2)];
    const float4v b = *(const float4v*)&lds[row * 64 + (((2 * gg + 1) ^ s) << 2)];
    union { uint32x4 u; short8 sv; } w;
    w.u[0] = pkbf(a[0], a[1]);
    w.u[1] = pkbf(a[2], a[3]);
    w.u[2] = pkbf(b[0], b[1]);
    w.u[3] = pkbf(b[2], b[3]);
    return w.sv;
  };

  float4v acc[2][2] = {};

  for (int k0 = 0; k0 < K; k0 += 64) {
    if (k0) __syncthreads();
    #pragma unroll
    for (int cc = 0; cc < 2; ++cc) {           // A: bf16 DMA, 16B cells
      const int row = wave * 16 + cc * 8 + r8;
      const int kg = skg ^ (row & 7);
      gll16(A + (size_t)(m0 + row) * K + k0 + kg * 8, &As[(wave * 16 + cc * 8) * 64]);
    }
    #pragma unroll
    for (int rr = 0; rr < 4; ++rr) {           // W: fp32 DMA, swizzled cells
      const int row = rr * 16 + wave * 4 + (lane >> 4);
      const int cl = (lane & 15) ^ (row & 15);
      gll16f(W + (size_t)(n0 + row) * K + k0 + cl * 4,
             &Wsf[(rr * 16 + wave * 4) * 64]);
    }
    __syncthreads();
    #pragma unroll
    for (int kk = 0; kk < 2; ++kk) {
      const int kg = ((kk * 4 + g) ^ sw) * 8;
      const int gg = kk * 4 + g;
      short8 xf[2], wf[2];
      #pragma unroll
      for (int t = 0; t < 2; ++t) {
        xf[t] = *(const short8*)&As[(wm + t * 16 + l16) * 64 + kg];
        wf[t] = f32frag(Wsf, wn + t * 16 + l16, gg);
      }
      #pragma unroll
      for (int i = 0; i < 2; ++i)
        #pragma unroll
        for (int j = 0; j < 2; ++j)
          acc[i][j] = __builtin_amdgcn_mfma_f32_16x16x32_bf16(wf[i], xf[j], acc[i][j], 0, 0, 0);
    }
  }

  // C layout: col=l16 -> m, row=4g+rr -> n.
  #pragma unroll
  for (int i = 0; i < 2; ++i) {
    const int nb = n0 + wn + i * 16 + 4 * g;
    const float4v bb = *(const float4v*)&bias[nb];
    #pragma unroll
    for (int j = 0; j < 2; ++j) {
      const int m = m0 + wm + j * 16 + l16;
      float4v ov;
      #pragma unroll
      for (int rr = 0; rr < 4; ++rr) ov[rr] = acc[i][j][rr] + bb[rr];
      *(float4v*)(Out + (size_t)m * N + nb) = ov;
    }
  }
}

extern "C" void kernel_launch(void* const* d_in, const int* in_sizes, int n_in,
                              void* d_out, int out_size, void* d_ws, size_t ws_size,
                              hipStream_t stream) {
  const float* q  = (const float*)d_in[0];
  const float* k  = (const float*)d_in[1];
  const float* v  = (const float*)d_in[2];
  const float* wq = (const float*)d_in[3];
  const float* bq = (const float*)d_in[4];
  const float* wk = (const float*)d_in[5];
  const float* bk = (const float*)d_in[6];
  const float* wv = (const float*)d_in[7];
  const float* bv = (const float*)d_in[8];
  const float* wo = (const float*)d_in[9];
  const float* bo = (const float*)d_in[10];
  float* out = (float*)d_out;

  const int S = 4096, D = 768;
  unsigned short* Qp    = (unsigned short*)d_ws;
  unsigned short* Kp    = Qp  + (size_t)S * D;
  unsigned short* Vt    = Kp  + (size_t)S * D;
  unsigned short* AO    = Vt  + (size_t)S * D;
  unsigned short* Opart = AO  + (size_t)S * D;            // 1536 * 8192 bf16 = 24 MB
  float*          lpart = (float*)(Opart + (size_t)1536 * 8192);  // 1536*128 f32

  const float SC = 0.125f * 1.44269504089f;  // (1/sqrt(64)) * log2(e), folded into Q
  dim3 blk(256);
  gemm_qkv<<<dim3(64, 12, 3), blk, 0, stream>>>(q, k, v, wq, wk, wv,
                                                bq, bk, bv, Qp, Kp, Vt, SC);
  flash_part<<<dim3(960), blk, 0, stream>>>(Qp, Kp, Vt, Opart, lpart);
  flash_combine<<<dim3(64, 12), blk, 0, stream>>>(Opart, lpart, AO);
  gemm_out<<<dim3(64, 12), blk, 0, stream>>>(AO, wo, bo, out);
}

// Round 13
// 189.485 us; speedup vs baseline: 1.0480x; 1.0480x over previous
//
#include <hip/hip_runtime.h>
#include <stdint.h>

typedef __attribute__((ext_vector_type(8))) short short8;
typedef __attribute__((ext_vector_type(2))) float float2v;
typedef __attribute__((ext_vector_type(4))) float float4v;
typedef __attribute__((ext_vector_type(16))) float f32x16;
typedef __attribute__((ext_vector_type(2))) uint32_t uint32x2;
typedef __attribute__((ext_vector_type(4))) uint32_t uint32x4;
typedef __attribute__((ext_vector_type(2))) unsigned int uint2v;

// v_cvt_pk_bf16_f32: 2 f32 -> packed 2x bf16 (RNE), single VALU op.
__device__ __forceinline__ uint32_t pkbf(float a, float b) {
  uint32_t r;
  asm("v_cvt_pk_bf16_f32 %0, %1, %2" : "=v"(r) : "v"(a), "v"(b));
  return r;
}

// packed 2xf32 add (VOP3P) for the softmax row-sum accumulation.
__device__ __forceinline__ float2v pkadd(float2v a, float2v b) {
  float2v d;
  asm("v_pk_add_f32 %0, %1, %2" : "=v"(d) : "v"(a), "v"(b));
  return d;
}

__device__ __forceinline__ float fexp2(float x) {
#if __has_builtin(__builtin_amdgcn_exp2f)
  return __builtin_amdgcn_exp2f(x);
#else
  return exp2f(x);
#endif
}

// permlane32_swap: exchanges vdst's high 32 lanes with vsrc's low 32 lanes.
__device__ __forceinline__ uint2v plswap(uint32_t a, uint32_t b) {
#if __has_builtin(__builtin_amdgcn_permlane32_swap)
  return __builtin_amdgcn_permlane32_swap(a, b, false, false);
#else
  asm("v_permlane32_swap_b32 %0, %1" : "+v"(a), "+v"(b));
  uint2v r;
  r[0] = a;
  r[1] = b;
  return r;
#endif
}

__device__ __forceinline__ void gll16(const unsigned short* g, unsigned short* l) {
  __builtin_amdgcn_global_load_lds(
      (const __attribute__((address_space(1))) void*)g,
      (__attribute__((address_space(3))) void*)l, 16, 0, 0);
}

// ---------------------------------------------------------------------------
// One-shot fp32 -> bf16 conversion for all 7 tensors (coalesced, 16B stores).
// Kept as a separate dispatch: every attempt to fuse conversion into GEMM
// staging (R7 reg-staged, R8 T14, R12 fragment-time) measured worse -- the
// bf16-everywhere pipeline with DMA staging is the verified optimum.
// ---------------------------------------------------------------------------
struct CvtArgs {
  const float* src[7];
  unsigned short* dst[7];
};

__global__ __launch_bounds__(256) void cvt_all(CvtArgs a) {
  const int bid = blockIdx.x;
  int t, off;
  if (bid < 4608) { t = bid / 1536; off = bid - t * 1536; }
  else { const int b2 = bid - 4608; t = 3 + b2 / 288; off = b2 - (t - 3) * 288; }
  const size_t i = (size_t)off * 256 + threadIdx.x;
  const float4v* p = (const float4v*)(a.src[t] + i * 8);
  float4v x = p[0], y = p[1];
  uint32x4 o;
  o[0] = pkbf(x[0], x[1]);
  o[1] = pkbf(x[2], x[3]);
  o[2] = pkbf(y[0], y[1]);
  o[3] = pkbf(y[2], y[3]);
  *(uint32x4*)(a.dst[t] + i * 8) = o;
}

// ---------------------------------------------------------------------------
// Fused QKV projection.  64x64 tile -> grid (64,12,3) = 2304 blocks,
// LDS 16KB -> 8 blocks/CU. bf16 inputs, DMA staging, XOR-swizzle.
// z=0 -> Qp (scaled), z=1 -> Kp, z=2 -> Vt [N][M].
// ---------------------------------------------------------------------------
__global__ __launch_bounds__(256) void gemm_qkv(
    const unsigned short* __restrict__ xq, const unsigned short* __restrict__ xk,
    const unsigned short* __restrict__ xv,
    const unsigned short* __restrict__ wqb, const unsigned short* __restrict__ wkb,
    const unsigned short* __restrict__ wvb,
    const float* __restrict__ bq, const float* __restrict__ bk,
    const float* __restrict__ bv,
    unsigned short* __restrict__ Qp, unsigned short* __restrict__ Kp,
    unsigned short* __restrict__ Vt, float qscale)
{
  __shared__ unsigned short As[64 * 64];
  __shared__ unsigned short Ws[64 * 64];
  const int z = blockIdx.z;
  const unsigned short* A = z == 0 ? xq : z == 1 ? xk : xv;
  const unsigned short* W = z == 0 ? wqb : z == 1 ? wkb : wvb;
  const float* bias = z == 0 ? bq : z == 1 ? bk : bv;
  const int M = 4096, N = 768, K = 768;
  const int tid = threadIdx.x, wave = tid >> 6, lane = tid & 63;
  const int g = lane >> 4, l16 = lane & 15;
  const int sw = l16 & 7;
  const int m0 = blockIdx.x * 64, n0 = blockIdx.y * 64;
  const int wm = (wave & 1) * 32, wn = (wave >> 1) * 32;
  const int r8 = lane >> 3, skg = lane & 7;

  float4v acc[2][2] = {};

  for (int k0 = 0; k0 < K; k0 += 64) {
    if (k0) __syncthreads();
    #pragma unroll
    for (int cc = 0; cc < 2; ++cc) {           // A: 64 rows, 16/wave
      const int row = wave * 16 + cc * 8 + r8;
      const int kg = skg ^ (row & 7);
      gll16(A + (size_t)(m0 + row) * K + k0 + kg * 8, &As[(wave * 16 + cc * 8) * 64]);
    }
    #pragma unroll
    for (int cc = 0; cc < 2; ++cc) {           // W: 64 rows, 16/wave
      const int row = wave * 16 + cc * 8 + r8;
      const int kg = skg ^ (row & 7);
      gll16(W + (size_t)(n0 + row) * K + k0 + kg * 8, &Ws[(wave * 16 + cc * 8) * 64]);
    }
    __syncthreads();
    #pragma unroll
    for (int kk = 0; kk < 2; ++kk) {
      const int kg = ((kk * 4 + g) ^ sw) * 8;
      short8 xf[2], wf[2];
      #pragma unroll
      for (int t = 0; t < 2; ++t) {
        xf[t] = *(const short8*)&As[(wm + t * 16 + l16) * 64 + kg];
        wf[t] = *(const short8*)&Ws[(wn + t * 16 + l16) * 64 + kg];
      }
      if (z < 2) {
        #pragma unroll
        for (int i = 0; i < 2; ++i)
          #pragma unroll
          for (int j = 0; j < 2; ++j)
            acc[i][j] = __builtin_amdgcn_mfma_f32_16x16x32_bf16(wf[i], xf[j], acc[i][j], 0, 0, 0);
      } else {
        #pragma unroll
        for (int b = 0; b < 2; ++b)
          #pragma unroll
          for (int a2 = 0; a2 < 2; ++a2)
            acc[b][a2] = __builtin_amdgcn_mfma_f32_16x16x32_bf16(xf[a2], wf[b], acc[b][a2], 0, 0, 0);
      }
    }
  }

  if (z < 2) {
    // C layout: col=l16 -> m, row=4g+rr -> n.
    unsigned short* O = z == 0 ? Qp : Kp;
    const float osc = z == 0 ? qscale : 1.0f;
    #pragma unroll
    for (int i = 0; i < 2; ++i) {
      const int nb = n0 + wn + i * 16 + 4 * g;
      const float4v bb = *(const float4v*)&bias[nb];
      #pragma unroll
      for (int j = 0; j < 2; ++j) {
        const int m = m0 + wm + j * 16 + l16;
        uint32x2 pk;
        pk[0] = pkbf((acc[i][j][0] + bb[0]) * osc, (acc[i][j][1] + bb[1]) * osc);
        pk[1] = pkbf((acc[i][j][2] + bb[2]) * osc, (acc[i][j][3] + bb[3]) * osc);
        *(uint32x2*)(O + (size_t)m * N + nb) = pk;
      }
    }
  } else {
    // C layout: col=l16 -> n, row=4g+rr -> m.
    #pragma unroll
    for (int b = 0; b < 2; ++b) {
      const int n = n0 + wn + b * 16 + l16;
      const float bb = bias[n];
      #pragma unroll
      for (int a2 = 0; a2 < 2; ++a2) {
        const int mb = m0 + wm + a2 * 16 + 4 * g;
        uint32x2 pk;
        pk[0] = pkbf(acc[b][a2][0] + bb, acc[b][a2][1] + bb);
        pk[1] = pkbf(acc[b][a2][2] + bb, acc[b][a2][3] + bb);
        *(uint32x2*)(Vt + (size_t)n * M + mb) = pk;
      }
    }
  }
}

// ---------------------------------------------------------------------------
// Flash attention PARTIAL kernel (R2 body, 47.3us verified; frozen).
// Fixed softmax (p = exp2(s)); swapped QK^T; in-register P (T12); PV via
// 32x32x16 with V^T A-frags from swizzled LDS. 32KB LDS -> 4 blocks/CU.
// ---------------------------------------------------------------------------
__global__ __launch_bounds__(256, 4) void flash_part(
    const unsigned short* __restrict__ Qp,  // [S][768] bf16, pre-scaled
    const unsigned short* __restrict__ Kp,  // [S][768] bf16
    const unsigned short* __restrict__ Vt,  // [768][S] bf16
    unsigned short* __restrict__ Opart,     // [1536 slots][128][64] bf16
    float* __restrict__ lpart)              // [1536 slots][128] fp32
{
  __shared__ unsigned short lds_k[2][64 * 64];
  __shared__ unsigned short lds_v[2][64 * 64];
  const int S = 4096, DM = 768;

  const int gid = blockIdx.x;
  const int h = gid % 12;
  const int e = 79 - gid / 12;
  int t, c;
  if (e < 8)       { t = e;                c = 0; }
  else if (e < 24) { t = 8 + (e - 8) / 2;  c = (e - 8) % 2; }
  else if (e < 48) { t = 16 + (e - 24) / 3; c = (e - 24) % 3; }
  else             { t = 24 + (e - 48) / 4; c = (e - 48) % 4; }
  const int kb0 = c * 16;
  const int kbe = min(kb0 + 16, 2 * t + 2);

  const int tid = threadIdx.x, wave = tid >> 6, lane = tid & 63;
  const int l31 = lane & 31, hi = lane >> 5, sw7 = lane & 7;
  const int qbase = t * 128 + wave * 32;
  const int qrow = qbase + l31;

  short8 qf[4];
  {
    const unsigned short* qp = Qp + (size_t)qrow * DM + h * 64 + hi * 8;
    qf[0] = *(const short8*)(qp);
    qf[1] = *(const short8*)(qp + 16);
    qf[2] = *(const short8*)(qp + 32);
    qf[3] = *(const short8*)(qp + 48);
  }

  f32x16 o0 = {}, o1 = {};            // O^T[d][q], d-tiles 0..31 / 32..63
  float2v lsA = {0.f, 0.f}, lsB = {0.f, 0.f};

  const int strow = wave * 16 + (lane >> 3);
  const int skg = lane & 7;

  #pragma unroll
  for (int cc = 0; cc < 2; ++cc) {
    const int row = strow + cc * 8;
    const int kg = skg ^ (row & 7);
    gll16(Kp + (size_t)(kb0 * 64 + row) * DM + h * 64 + kg * 8,
          &lds_k[0][(wave * 16 + cc * 8) * 64]);
    gll16(Vt + (size_t)(h * 64 + row) * S + kb0 * 64 + kg * 8,
          &lds_v[0][(wave * 16 + cc * 8) * 64]);
  }
  __syncthreads();

  for (int kb = kb0; kb < kbe; ++kb) {
    const int cur = kb & 1;
    if (kb + 1 < kbe) {
      const int nb = cur ^ 1;
      #pragma unroll
      for (int cc = 0; cc < 2; ++cc) {
        const int row = strow + cc * 8;
        const int kg = skg ^ (row & 7);
        gll16(Kp + (size_t)((kb + 1) * 64 + row) * DM + h * 64 + kg * 8,
              &lds_k[nb][(wave * 16 + cc * 8) * 64]);
        gll16(Vt + (size_t)(h * 64 + row) * S + (kb + 1) * 64 + kg * 8,
              &lds_v[nb][(wave * 16 + cc * 8) * 64]);
      }
    }
    const unsigned short* kc = lds_k[cur];
    const unsigned short* vc = lds_v[cur];

    f32x16 s0 = {}, s1 = {};
    __builtin_amdgcn_s_setprio(1);
    #pragma unroll
    for (int d4 = 0; d4 < 4; ++d4) {
      const int cg = ((2 * d4 + hi) ^ sw7) * 8;
      short8 ka = *(const short8*)&kc[l31 * 64 + cg];
      short8 kb2 = *(const short8*)&kc[(32 + l31) * 64 + cg];
      s0 = __builtin_amdgcn_mfma_f32_32x32x16_bf16(ka, qf[d4], s0, 0, 0, 0);
      s1 = __builtin_amdgcn_mfma_f32_32x32x16_bf16(kb2, qf[d4], s1, 0, 0, 0);
    }
    __builtin_amdgcn_s_setprio(0);

    const bool diag = (kb + 1) * 64 > qbase;
    short8 pb[4];
    auto sm_pack = [&](const f32x16& sv, int ks, short8* pbp) {
      #pragma unroll
      for (int jh = 0; jh < 2; ++jh) {
        float pe[8];
        if (diag) {
          #pragma unroll
          for (int rr = 0; rr < 8; ++rr) {
            const int key = kb * 64 + ks + (rr & 3) + 8 * (2 * jh + (rr >> 2)) + 4 * hi;
            pe[rr] = fexp2(key <= qrow ? sv[jh * 8 + rr] : -1e30f);
          }
        } else {
          #pragma unroll
          for (int rr = 0; rr < 8; ++rr) pe[rr] = fexp2(sv[jh * 8 + rr]);
        }
        float2v p01 = {pe[0], pe[1]}, p23 = {pe[2], pe[3]};
        float2v p45 = {pe[4], pe[5]}, p67 = {pe[6], pe[7]};
        lsA = pkadd(lsA, pkadd(p01, p45));
        lsB = pkadd(lsB, pkadd(p23, p67));
        const uint32_t x01 = pkbf(pe[0], pe[1]);
        const uint32_t x23 = pkbf(pe[2], pe[3]);
        const uint32_t y01 = pkbf(pe[4], pe[5]);
        const uint32_t y23 = pkbf(pe[6], pe[7]);
        uint2v r01 = plswap(x01, y01);
        uint2v r23 = plswap(x23, y23);
        union { uint32x4 u; short8 s; } w;
        w.u[0] = r01[0];
        w.u[1] = r23[0];
        w.u[2] = r01[1];
        w.u[3] = r23[1];
        pbp[jh] = w.s;
      }
    };
    sm_pack(s0, 0, &pb[0]);
    sm_pack(s1, 32, &pb[2]);

    __builtin_amdgcn_s_setprio(1);
    #pragma unroll
    for (int kk = 0; kk < 4; ++kk) {
      const int cg = ((2 * kk + hi) ^ sw7) * 8;
      short8 va0 = *(const short8*)&vc[l31 * 64 + cg];
      short8 va1 = *(const short8*)&vc[(32 + l31) * 64 + cg];
      o0 = __builtin_amdgcn_mfma_f32_32x32x16_bf16(va0, pb[kk], o0, 0, 0, 0);
      o1 = __builtin_amdgcn_mfma_f32_32x32x16_bf16(va1, pb[kk], o1, 0, 0, 0);
    }
    __builtin_amdgcn_s_setprio(0);

    __syncthreads();  // drain prefetch DMA + protect buffer reuse
  }

  // epilogue: unnormalized partial write
  float L = (lsA[0] + lsA[1]) + (lsB[0] + lsB[1]);
  L += __shfl_xor(L, 32);
  const int slot = (h * 32 + t) * 4 + c;
  if (hi == 0) lpart[slot * 128 + wave * 32 + l31] = L;
  unsigned short* ob = Opart + (size_t)slot * 8192 + (size_t)(wave * 32 + l31) * 64;
  #pragma unroll
  for (int dt = 0; dt < 2; ++dt) {
    const f32x16& oo = dt ? o1 : o0;
    #pragma unroll
    for (int a = 0; a < 4; ++a) {
      uint32x2 ov;
      ov[0] = pkbf(oo[4 * a + 0], oo[4 * a + 1]);
      ov[1] = pkbf(oo[4 * a + 2], oo[4 * a + 3]);
      *(uint32x2*)(ob + dt * 32 + 8 * a + 4 * hi) = ov;
    }
  }
}

// ---------------------------------------------------------------------------
// Combine partials. Grid (64,12), 64 q-rows/block -> 768 blocks = 3/CU.
// ---------------------------------------------------------------------------
__global__ __launch_bounds__(256) void flash_combine(
    const unsigned short* __restrict__ Opart, const float* __restrict__ lpart,
    unsigned short* __restrict__ AO)
{
  const int t2 = blockIdx.x, h = blockIdx.y;
  const int t = t2 >> 1;
  const int nc = (2 * t + 17) >> 4;          // ceil((2t+2)/16)
  const int slot0 = (h * 32 + t) * 4;
  const int tid = threadIdx.x;
  const int qr = tid >> 2, dc = (tid & 3) * 16;
  const int ql = (t2 & 1) * 64 + qr;         // row within the 128-row tile
  float acc[16];
  #pragma unroll
  for (int j = 0; j < 16; ++j) acc[j] = 0.0f;
  float lsum = 0.0f;
  for (int cc = 0; cc < nc; ++cc) {
    const int slot = slot0 + cc;
    lsum += lpart[slot * 128 + ql];
    const uint32x4* p = (const uint32x4*)(Opart + (size_t)slot * 8192 + ql * 64 + dc);
    uint32x4 w0 = p[0], w1 = p[1];
    #pragma unroll
    for (int j = 0; j < 4; ++j) {
      union { uint32_t u; float f; } lo, hi;
      lo.u = w0[j] << 16; hi.u = w0[j] & 0xffff0000u;
      acc[2 * j] += lo.f; acc[2 * j + 1] += hi.f;
      lo.u = w1[j] << 16; hi.u = w1[j] & 0xffff0000u;
      acc[8 + 2 * j] += lo.f; acc[8 + 2 * j + 1] += hi.f;
    }
  }
  const float inv = 1.0f / lsum;
  uint32x4 o0, o1;
  #pragma unroll
  for (int j = 0; j < 4; ++j) {
    o0[j] = pkbf(acc[2 * j] * inv, acc[2 * j + 1] * inv);
    o1[j] = pkbf(acc[8 + 2 * j] * inv, acc[8 + 2 * j + 1] * inv);
  }
  unsigned short* dst = AO + (size_t)(t * 128 + ql) * 768 + h * 64 + dc;
  *(uint32x4*)dst = o0;
  *(uint32x4*)(dst + 8) = o1;
}

// ---------------------------------------------------------------------------
// Output projection (64x64 tile, 768 blocks = 3/CU, both operands bf16
// DMA-staged). C^T write.
// ---------------------------------------------------------------------------
__global__ __launch_bounds__(256) void gemm_out(
    const unsigned short* __restrict__ A, const unsigned short* __restrict__ W,
    const float* __restrict__ bias, float* __restrict__ Out)
{
  __shared__ unsigned short As[64 * 64];
  __shared__ unsigned short Ws[64 * 64];
  const int N = 768, K = 768;
  const int tid = threadIdx.x, wave = tid >> 6, lane = tid & 63;
  const int g = lane >> 4, l16 = lane & 15;
  const int sw = l16 & 7;
  const int m0 = blockIdx.x * 64, n0 = blockIdx.y * 64;
  const int wm = (wave & 1) * 32, wn = (wave >> 1) * 32;
  const int r8 = lane >> 3, skg = lane & 7;

  float4v acc[2][2] = {};

  for (int k0 = 0; k0 < K; k0 += 64) {
    if (k0) __syncthreads();
    #pragma unroll
    for (int cc = 0; cc < 2; ++cc) {
      const int row = wave * 16 + cc * 8 + r8;
      const int kg = skg ^ (row & 7);
      gll16(A + (size_t)(m0 + row) * K + k0 + kg * 8, &As[(wave * 16 + cc * 8) * 64]);
    }
    #pragma unroll
    for (int cc = 0; cc < 2; ++cc) {
      const int row = wave * 16 + cc * 8 + r8;
      const int kg = skg ^ (row & 7);
      gll16(W + (size_t)(n0 + row) * K + k0 + kg * 8, &Ws[(wave * 16 + cc * 8) * 64]);
    }
    __syncthreads();
    #pragma unroll
    for (int kk = 0; kk < 2; ++kk) {
      const int kg = ((kk * 4 + g) ^ sw) * 8;
      short8 xf[2], wf[2];
      #pragma unroll
      for (int t = 0; t < 2; ++t) {
        xf[t] = *(const short8*)&As[(wm + t * 16 + l16) * 64 + kg];
        wf[t] = *(const short8*)&Ws[(wn + t * 16 + l16) * 64 + kg];
      }
      #pragma unroll
      for (int i = 0; i < 2; ++i)
        #pragma unroll
        for (int j = 0; j < 2; ++j)
          acc[i][j] = __builtin_amdgcn_mfma_f32_16x16x32_bf16(wf[i], xf[j], acc[i][j], 0, 0, 0);
    }
  }

  // C layout: col=l16 -> m, row=4g+rr -> n.
  #pragma unroll
  for (int i = 0; i < 2; ++i) {
    const int nb = n0 + wn + i * 16 + 4 * g;
    const float4v bb = *(const float4v*)&bias[nb];
    #pragma unroll
    for (int j = 0; j < 2; ++j) {
      const int m = m0 + wm + j * 16 + l16;
      float4v ov;
      #pragma unroll
      for (int rr = 0; rr < 4; ++rr) ov[rr] = acc[i][j][rr] + bb[rr];
      *(float4v*)(Out + (size_t)m * N + nb) = ov;
    }
  }
}

extern "C" void kernel_launch(void* const* d_in, const int* in_sizes, int n_in,
                              void* d_out, int out_size, void* d_ws, size_t ws_size,
                              hipStream_t stream) {
  const float* q  = (const float*)d_in[0];
  const float* k  = (const float*)d_in[1];
  const float* v  = (const float*)d_in[2];
  const float* wq = (const float*)d_in[3];
  const float* bq = (const float*)d_in[4];
  const float* wk = (const float*)d_in[5];
  const float* bk = (const float*)d_in[6];
  const float* wv = (const float*)d_in[7];
  const float* bv = (const float*)d_in[8];
  const float* wo = (const float*)d_in[9];
  const float* bo = (const float*)d_in[10];
  float* out = (float*)d_out;

  const int S = 4096, D = 768;
  unsigned short* Qp    = (unsigned short*)d_ws;
  unsigned short* Kp    = Qp  + (size_t)S * D;
  unsigned short* Vt    = Kp  + (size_t)S * D;
  unsigned short* AO    = Vt  + (size_t)S * D;
  unsigned short* xq    = AO  + (size_t)S * D;
  unsigned short* xk    = xq  + (size_t)S * D;
  unsigned short* xv    = xk  + (size_t)S * D;
  unsigned short* wqb   = xv  + (size_t)S * D;
  unsigned short* wkb   = wqb + (size_t)D * D;
  unsigned short* wvb   = wkb + (size_t)D * D;
  unsigned short* wob   = wvb + (size_t)D * D;
  unsigned short* Opart = wob + (size_t)D * D;            // 1536 * 8192 bf16 = 24 MB
  float*          lpart = (float*)(Opart + (size_t)1536 * 8192);  // 1536*128 f32

  CvtArgs ca;
  ca.src[0] = q;  ca.dst[0] = xq;
  ca.src[1] = k;  ca.dst[1] = xk;
  ca.src[2] = v;  ca.dst[2] = xv;
  ca.src[3] = wq; ca.dst[3] = wqb;
  ca.src[4] = wk; ca.dst[4] = wkb;
  ca.src[5] = wv; ca.dst[5] = wvb;
  ca.src[6] = wo; ca.dst[6] = wob;

  const float SC = 0.125f * 1.44269504089f;  // (1/sqrt(64)) * log2(e), folded into Q
  dim3 blk(256);
  cvt_all<<<dim3(5760), blk, 0, stream>>>(ca);
  gemm_qkv<<<dim3(64, 12, 3), blk, 0, stream>>>(xq, xk, xv, wqb, wkb, wvb,
                                                bq, bk, bv, Qp, Kp, Vt, SC);
  flash_part<<<dim3(960), blk, 0, stream>>>(Qp, Kp, Vt, Opart, lpart);
  flash_combine<<<dim3(64, 12), blk, 0, stream>>>(Opart, lpart, AO);
  gemm_out<<<dim3(64, 12), blk, 0, stream>>>(AO, wob, bo, out);
}